// Round 7
// baseline (155.449 us; speedup 1.0000x reference)
//
#include <hip/hip_runtime.h>
#include <hip/hip_bf16.h>
#include <stdint.h>
#include <stddef.h>

#define NB 8
#define NT 2048
#define NC 1024
#define NH 128

typedef float f32x4 __attribute__((ext_vector_type(4)));
typedef short bf16x8 __attribute__((ext_vector_type(8)));
typedef short bf16x4 __attribute__((ext_vector_type(4)));

__device__ __forceinline__ unsigned short f2bf(float f) {
    union { float f; uint32_t u; } v; v.f = f;
    uint32_t u = v.u;
    u += 0x7fffu + ((u >> 16) & 1u);   // round-to-nearest-even
    return (unsigned short)(u >> 16);
}

// Direct global->LDS copy, 16 B/lane. lp must be wave-uniform.
__device__ __forceinline__ void gld16(const void* gp, void* lp) {
    __builtin_amdgcn_global_load_lds(
        (const __attribute__((address_space(1))) unsigned int*)gp,
        (__attribute__((address_space(3))) unsigned int*)lp, 16, 0, 0);
}

// ===========================================================================
// Fragment-order layouts (1 KB per 64-lane fragment, lane = quad*16 + l16):
//   Qf/Kf [b][i=128][ks=4] : lane holds X[t=i*16+l16][h=ks*32+quad*8+j]
//   Vf    [b][nt=8][tc=64] : lane holds V[t=tc*32+quad*8+j][h=nt*16+l16]
//   Wtf   [g=24][kb=32]    : lane holds W_{g>>3}[k=kb*32+quad*8+j][n=(g&7)*16+l16]
// ===========================================================================

// ---------------------------------------------------------------------------
// Kernel 1: W fp32 [1024][128] -> Wtf fragment order. 192 blocks.
// ---------------------------------------------------------------------------
__global__ __launch_bounds__(256) void cast_w_kernel(const float* __restrict__ Wq,
                                                     const float* __restrict__ Wk,
                                                     const float* __restrict__ Wv,
                                                     unsigned short* __restrict__ Wtf) {
    int gid  = blockIdx.x * 256 + threadIdx.x;   // 0..49151
    int lane = gid & 63;
    int fs   = gid >> 6;                         // g*32 + kb
    int kb   = fs & 31;
    int g    = fs >> 5;                          // 0..23
    int w    = g >> 3;
    int g16  = g & 7;
    int quad = lane >> 4;
    int l16  = lane & 15;
    const float* src = (w == 0) ? Wq : ((w == 1) ? Wk : Wv);
    int n = g16 * 16 + l16;
    bf16x8 o;
#pragma unroll
    for (int j = 0; j < 8; ++j)
        o[j] = (short)f2bf(src[(size_t)(kb * 32 + quad * 8 + j) * 128 + n]);
    *(bf16x8*)(Wtf + (size_t)gid * 8) = o;
}

// ---------------------------------------------------------------------------
// Kernel 2: FUSED QKV projection — v4 "coalesced-x" RESTORED VERBATIM (best
// measured: 43.2 µs, R5). 1 blk/CU, 512 thr, counted-vmcnt barriers,
// coalesced x staged through swizzled LDS, W 4-buffer stage k+3.
// (R6 lesson: 2 blk/CU + draining barriers = 56 µs; counted > drain, m218.)
// ---------------------------------------------------------------------------
#define CS2 392   // epilogue cs stride (shorts); 784 B = 49*16

__global__ __launch_bounds__(512, 2) void proj_kernel(const float* __restrict__ x,
                                                      const unsigned short* __restrict__ Wtf,
                                                      unsigned short* __restrict__ Qf,
                                                      unsigned short* __restrict__ Kf,
                                                      unsigned short* __restrict__ Vf) {
    __shared__ __align__(16) unsigned short wbuf[4][24 * 512];   // 96 KB; cs overlays
    __shared__ __align__(16) unsigned short abuf[2][64 * 128];   // 32 KB, row stride 256 B

    const int tid  = threadIdx.x;
    const int wave = tid >> 6;             // 0..7
    const int lane = tid & 63;
    const int quad = lane >> 4;
    const int l16  = lane & 15;
    const int bidx = blockIdx.x;           // 0..255
    const int rowbase = bidx * 64;
    const int b    = bidx >> 5;            // batch
    const int mh   = wave & 1;             // m-half (32 rows)
    const int nq   = wave >> 1;            // n-quarter (96 cols)

    const int arow = wave * 8 + (lane >> 3);
    const float* axp = x + (size_t)(rowbase + arow) * NC;
    const int aswz = (arow & 7) << 3;      // write swizzle (short-index XOR)
    const int rswz = (l16 & 7) << 3;       // read swizzle

    float4 aS[2][4];
    f32x4 acc0[6] = {};
    f32x4 acc1[6] = {};

#define STAGE(KB, BI) { _Pragma("unroll") \
    for (int i_ = 0; i_ < 3; ++i_) { \
        const int g_ = wave * 3 + i_; \
        gld16(Wtf + ((size_t)(g_ * 32 + (KB)) * 512) + lane * 8, &wbuf[BI][g_ * 512]); } }

#define LOADA(C, S) { _Pragma("unroll") \
    for (int i_ = 0; i_ < 4; ++i_) \
        aS[S][i_] = *(const float4*)(axp + (C) * 128 + i_ * 32 + (lane & 7) * 4); }

#define DSWRITE(C, S) { _Pragma("unroll") \
    for (int i_ = 0; i_ < 4; ++i_) { \
        bf16x4 t_; \
        t_[0] = (short)f2bf(aS[S][i_].x); t_[1] = (short)f2bf(aS[S][i_].y); \
        t_[2] = (short)f2bf(aS[S][i_].z); t_[3] = (short)f2bf(aS[S][i_].w); \
        *(bf16x4*)(&abuf[(C) & 1][arow * 128 + ((i_ * 32 + (lane & 7) * 4) ^ aswz)]) = t_; } }

#define BARW(N) { asm volatile("s_waitcnt vmcnt(" #N ") lgkmcnt(0)" ::: "memory"); \
                  __builtin_amdgcn_s_barrier(); }

#define TICK(K, CUR) { \
    const unsigned short* ab_ = abuf[((K) >> 2) & 1]; \
    const int t2_ = ((K) & 3) * 32 + quad * 8; \
    bf16x8 af0 = *(const bf16x8*)(ab_ + (mh * 32 + l16) * 128 + (t2_ ^ rswz)); \
    bf16x8 af1 = *(const bf16x8*)(ab_ + (mh * 32 + 16 + l16) * 128 + (t2_ ^ rswz)); \
    _Pragma("unroll") \
    for (int i_ = 0; i_ < 6; ++i_) { \
        bf16x8 wf_ = *(const bf16x8*)(&wbuf[CUR][(nq * 6 + i_) * 512 + lane * 8]); \
        acc0[i_] = __builtin_amdgcn_mfma_f32_16x16x32_bf16(af0, wf_, acc0[i_], 0, 0, 0); \
        acc1[i_] = __builtin_amdgcn_mfma_f32_16x16x32_bf16(af1, wf_, acc1[i_], 0, 0, 0); } }

    // ---- prologue ----
    LOADA(0, 0); LOADA(1, 1);
    STAGE(0, 0); STAGE(1, 1); STAGE(2, 2);
    asm volatile("s_waitcnt vmcnt(13)" ::: "memory");   // retire A(0)
    DSWRITE(0, 0);
    BARW(6);                                            // retire st(0)

    for (int c = 0; c < 6; ++c) {
        const int k0 = c * 4;
        LOADA(c + 2, c & 1);
        STAGE(k0 + 3, 3); TICK(k0 + 0, 0); BARW(10);
        STAGE(k0 + 4, 0); TICK(k0 + 1, 1); BARW(10);
        STAGE(k0 + 5, 1); TICK(k0 + 2, 2); BARW(6);
        STAGE(k0 + 6, 2); TICK(k0 + 3, 3); DSWRITE(c + 1, (c + 1) & 1); BARW(6);
    }
    STAGE(27, 3); TICK(24, 0); BARW(6);
    STAGE(28, 0); TICK(25, 1); BARW(6);
    STAGE(29, 1); TICK(26, 2); BARW(6);
    STAGE(30, 2); TICK(27, 3); DSWRITE(7, 1); BARW(6);
    STAGE(31, 3); TICK(28, 0); BARW(6);
    TICK(29, 1); BARW(3);
    TICK(30, 2); BARW(0);
    TICK(31, 3);
    asm volatile("s_waitcnt vmcnt(0) lgkmcnt(0)" ::: "memory");
    __builtin_amdgcn_s_barrier();

    // ---- epilogue ----
    unsigned short* cs = (unsigned short*)wbuf;   // [64][CS2]
#pragma unroll
    for (int i = 0; i < 6; ++i) {
#pragma unroll
        for (int r = 0; r < 4; ++r) {
            cs[(mh * 32 +  0 + quad * 4 + r) * CS2 + nq * 96 + i * 16 + l16] = f2bf(acc0[i][r]);
            cs[(mh * 32 + 16 + quad * 4 + r) * CS2 + nq * 96 + i * 16 + l16] = f2bf(acc1[i][r]);
        }
    }
    __syncthreads();

    const int ibase = (rowbase & (NT - 1)) >> 4;
    const int tc    = (rowbase & (NT - 1)) >> 5;
    unsigned short* qdst = Qf + (size_t)b * (NT * NH);
    unsigned short* kdst = Kf + (size_t)b * (NT * NH);
    unsigned short* vdst = Vf + (size_t)b * (NT * NH);

#pragma unroll
    for (int j = 0; j < 6; ++j) {
        const int s = wave * 6 + j;
        if (s < 32) {
            const int isK = s >> 4;
            const int t   = s & 15;
            const int m   = t >> 2;
            const int ks  = t & 3;
            unsigned short* dst = isK ? kdst : qdst;
            bf16x8 v = *(const bf16x8*)(&cs[(m * 16 + l16) * CS2 + isK * 128 + ks * 32 + quad * 8]);
            *(bf16x8*)(dst + ((size_t)((ibase + m) * 4 + ks) * 64 + lane) * 8) = v;
        } else {
            const int vv = s - 32;
            const int nt = vv >> 1;
            const int cc = vv & 1;
            bf16x8 v;
#pragma unroll
            for (int jj = 0; jj < 8; ++jj)
                v[jj] = (short)cs[(cc * 32 + quad * 8 + jj) * CS2 + 256 + nt * 16 + l16];
            *(bf16x8*)(vdst + ((size_t)(nt * 64 + tc + cc) * 64 + lane) * 8) = v;
        }
    }

#undef TICK
#undef BARW
#undef DSWRITE
#undef LOADA
#undef STAGE
}

// ---------------------------------------------------------------------------
// Kernel 3: flash attention, v3 "counted pipeline".
// Grid 256 (1 blk/CU), 512 threads (8 waves), block = 64 q-rows.
// Wave = (mh = w&1, kh = (w>>1)&1, nh = w>>2); kq = kh*2+nh.
// 32 iters of 64-key tiles, TRIPLE-buffered (K 3x16 + V 3x16 = 96 KB),
// stage(j+2) issued at iter j, end-of-iter barrier uses vmcnt(4) (the 4
// newest = this iter's stage) — no drains in the main loop (T3+T4).
// S-phase: wave computes 16 keys (kq) x 32 rows (2 m-tiles): 8 MFMA.
// P shared within (mh,kh) group via LDS; mid-iter lgkmcnt(0)+s_barrier
// (raw, no vmcnt drain) makes it visible.
// PV-phase: wave does key-chunk kh (32 keys), cols nh*64..+64 (4 nt):
// 8 MFMA, k=32. 2-way kh-merge at end through LDS overlay.
// Max-free softmax, XCD-pinned batches.
// ---------------------------------------------------------------------------
#define AKBUF(BI) (smem + (size_t)(BI) * 8192)
#define AVBUF(BI) (smem + 24576 + (size_t)(BI) * 8192)

__global__ __launch_bounds__(512, 1) void attn_kernel(const unsigned short* __restrict__ Qf,
                                                      const unsigned short* __restrict__ Kf,
                                                      const unsigned short* __restrict__ Vf,
                                                      float* __restrict__ out) {
    // shorts: K tiles [3][16*512] | V tiles [3][16*512] = 96 KB; od overlays
    __shared__ __align__(16) unsigned short smem[6 * 16 * 512];
    __shared__ __align__(16) unsigned short p_grp[4][32 * 40];   // 10 KB
    __shared__ float sl[8][32];                                  // 1 KB

    const int tid  = threadIdx.x;
    const int wave = tid >> 6;             // 0..7
    const int lane = tid & 63;
    const int quad = lane >> 4;
    const int l16  = lane & 15;
    const int bid  = blockIdx.x;           // 0..255
    const int b    = bid & 7;              // XCD pin
    const int iqg  = bid >> 3;             // 0..31 (64-row group)
    const int mh   = wave & 1;             // m-half (32 rows)
    const int kh   = (wave >> 1) & 1;      // key-chunk (32 of 64)
    const int nh   = wave >> 2;            // output col-half (64 of 128)
    const int kq   = kh * 2 + nh;          // S-phase key-16 index in tile

    const unsigned short* qfp = Qf + (size_t)b * (NT * NH);
    const unsigned short* kfp = Kf + (size_t)b * (NT * NH);
    const unsigned short* vfp = Vf + (size_t)b * (NT * NH);
    unsigned short* pg = p_grp[mh * 2 + kh];

    // Q frags for this wave's two 16-row m-tiles
    const int iq0 = iqg * 4 + mh * 2;
    bf16x8 qf0[4], qf1[4];
#pragma unroll
    for (int ks = 0; ks < 4; ++ks) {
        qf0[ks] = *(const bf16x8*)(qfp + ((size_t)((iq0 + 0) * 4 + ks) * 64 + lane) * 8);
        qf1[ks] = *(const bf16x8*)(qfp + ((size_t)((iq0 + 1) * 4 + ks) * 64 + lane) * 8);
    }

    // stage 64-key tile j: 16 K frags + 16 V frags; 4 gld16/wave
    auto stage = [&](int j, int bi) {
#pragma unroll
        for (int i = 0; i < 4; ++i) {
            const int fid = wave * 4 + i;
            if (fid < 16) {
                gld16(kfp + ((size_t)(j * 16 + fid) * 512) + lane * 8, AKBUF(bi) + fid * 512);
            } else {
                const int s  = fid - 16;       // nt*2 + c
                const int nt = s >> 1;
                const int c  = s & 1;
                gld16(vfp + ((size_t)(nt * 64 + j * 2 + c) * 512) + lane * 8, AVBUF(bi) + s * 512);
            }
        }
    };

    // prologue: stage tiles 0,1; retire stage0 (stage1's 4 ops stay in flight)
    stage(0, 0);
    stage(1, 1);
    asm volatile("s_waitcnt vmcnt(4)" ::: "memory");
    __builtin_amdgcn_s_barrier();

    f32x4 O0[4] = {}, O1[4] = {};          // [nt-local] x 2 m-tiles
    float lsum0[4] = {0.f, 0.f, 0.f, 0.f};
    float lsum1[4] = {0.f, 0.f, 0.f, 0.f};
    const float scl2 = 0.03125f * 1.44269504088896340736f;  // (1/sqrt(C))*log2(e)

    for (int j = 0; j < 32; ++j) {
        const int cur = j - (j / 3) * 3;   // j % 3
        const int nxt = (j + 2 >= 3 * ((j + 2) / 3)) ? (j + 2) - 3 * ((j + 2) / 3) : 0;
        if (j < 30) stage(j + 2, nxt);
        const unsigned short* kb = AKBUF(cur);
        const unsigned short* vb = AVBUF(cur);

        // ---- S = Q K^T : this wave's 16 keys (kq) x 2 m-tiles ----
        f32x4 S0 = {}, S1 = {};
#pragma unroll
        for (int ks = 0; ks < 4; ++ks) {
            bf16x8 kf = *(const bf16x8*)(kb + (kq * 4 + ks) * 512 + lane * 8);
            S0 = __builtin_amdgcn_mfma_f32_16x16x32_bf16(qf0[ks], kf, S0, 0, 0, 0);
            S1 = __builtin_amdgcn_mfma_f32_16x16x32_bf16(qf1[ks], kf, S1, 0, 0, 0);
        }

        // ---- P = exp2(S*scl2); lsum; P -> group LDS (cols nh*16..+16) ----
#pragma unroll
        for (int r = 0; r < 4; ++r) {
            float p0 = __builtin_amdgcn_exp2f(S0[r] * scl2);
            float p1 = __builtin_amdgcn_exp2f(S1[r] * scl2);
            lsum0[r] += p0;
            lsum1[r] += p1;
            pg[(quad * 4 + r) * 40 + nh * 16 + l16]        = f2bf(p0);
            pg[(16 + quad * 4 + r) * 40 + nh * 16 + l16]   = f2bf(p1);
        }

        // ---- make P visible to the (mh,kh) sibling; NO vmcnt drain ----
        asm volatile("s_waitcnt lgkmcnt(0)" ::: "memory");
        __builtin_amdgcn_s_barrier();

        // ---- O += P V : chunk kh (32 keys), cols nh*64..+64 ----
        bf16x8 pf0 = *(const bf16x8*)(&pg[l16 * 40 + quad * 8]);
        bf16x8 pf1 = *(const bf16x8*)(&pg[(16 + l16) * 40 + quad * 8]);
#pragma unroll
        for (int i = 0; i < 4; ++i) {
            const int nt = nh * 4 + i;
            bf16x8 vf = *(const bf16x8*)(vb + (nt * 2 + kh) * 512 + lane * 8);
            O0[i] = __builtin_amdgcn_mfma_f32_16x16x32_bf16(pf0, vf, O0[i], 0, 0, 0);
            O1[i] = __builtin_amdgcn_mfma_f32_16x16x32_bf16(pf1, vf, O1[i], 0, 0, 0);
        }

        // ---- end-of-iter: retire stage(j+1) only; keep stage(j+2) flying ----
        if (j < 30) {
            asm volatile("s_waitcnt vmcnt(4) lgkmcnt(0)" ::: "memory");
        } else {
            asm volatile("s_waitcnt vmcnt(0) lgkmcnt(0)" ::: "memory");
        }
        __builtin_amdgcn_s_barrier();
    }

    // ---- reduce lsum across the 16 lanes holding each row ----
#pragma unroll
    for (int msk = 1; msk <= 8; msk <<= 1) {
#pragma unroll
        for (int r = 0; r < 4; ++r) {
            lsum0[r] += __shfl_xor(lsum0[r], msk, 64);
            lsum1[r] += __shfl_xor(lsum1[r], msk, 64);
        }
    }
    if (l16 == 0) {
#pragma unroll
        for (int r = 0; r < 4; ++r) {
            sl[wave][quad * 4 + r]      = lsum0[r];
            sl[wave][16 + quad * 4 + r] = lsum1[r];
        }
    }
    __syncthreads();

    // ---- 2-way kh-merge through LDS overlay on smem ----
    float* od = (float*)smem;   // [4][32][68] floats = 34.8 KB
    const int g = nh * 2 + mh;
    if (kh == 1) {
        float* myod = od + (size_t)g * 32 * 68;
#pragma unroll
        for (int i = 0; i < 4; ++i) {
#pragma unroll
            for (int r = 0; r < 4; ++r) {
                myod[(quad * 4 + r) * 68 + i * 16 + l16]      = O0[i][r];
                myod[(16 + quad * 4 + r) * 68 + i * 16 + l16] = O1[i][r];
            }
        }
    }
    __syncthreads();

    if (kh == 0) {
        // denominator: 4 waves share mh: {mh, mh+2, mh+4, mh+6}
        float inv0[4], inv1[4];
#pragma unroll
        for (int r = 0; r < 4; ++r) {
            inv0[r] = 1.0f / (sl[mh][quad * 4 + r] + sl[2 + mh][quad * 4 + r] +
                              sl[4 + mh][quad * 4 + r] + sl[6 + mh][quad * 4 + r]);
            inv1[r] = 1.0f / (sl[mh][16 + quad * 4 + r] + sl[2 + mh][16 + quad * 4 + r] +
                              sl[4 + mh][16 + quad * 4 + r] + sl[6 + mh][16 + quad * 4 + r]);
        }
        const float* pod = od + (size_t)g * 32 * 68;
        float* orow = out + ((size_t)b * NT + iqg * 64 + mh * 32) * NH + nh * 64;
#pragma unroll
        for (int i = 0; i < 4; ++i) {
#pragma unroll
            for (int r = 0; r < 4; ++r) {
                float v0 = O0[i][r] + pod[(quad * 4 + r) * 68 + i * 16 + l16];
                float v1 = O1[i][r] + pod[(16 + quad * 4 + r) * 68 + i * 16 + l16];
                orow[(quad * 4 + r) * NH + i * 16 + l16]      = v0 * inv0[r];
                orow[(16 + quad * 4 + r) * NH + i * 16 + l16] = v1 * inv1[r];
            }
        }
    }
}

#undef AKBUF
#undef AVBUF

// ---------------------------------------------------------------------------
extern "C" void kernel_launch(void* const* d_in, const int* in_sizes, int n_in,
                              void* d_out, int out_size, void* d_ws, size_t ws_size,
                              hipStream_t stream) {
    const float* x  = (const float*)d_in[0];
    const float* Wk = (const float*)d_in[1];
    const float* Wq = (const float*)d_in[2];
    const float* Wv = (const float*)d_in[3];
    float* out = (float*)d_out;

    char* ws = (char*)d_ws;
    unsigned short* Qf  = (unsigned short*)(ws);                      //  4 MB
    unsigned short* Kf  = (unsigned short*)(ws + 4194304);            //  4 MB
    unsigned short* Vf  = (unsigned short*)(ws + 8388608);            //  4 MB
    unsigned short* Wtf = (unsigned short*)(ws + 12582912);           //  0.75 MB

    cast_w_kernel<<<192, 256, 0, stream>>>(Wq, Wk, Wv, Wtf);
    proj_kernel<<<256, 512, 0, stream>>>(x, Wtf, Qf, Kf, Vf);
    attn_kernel<<<256, 512, 0, stream>>>(Qf, Kf, Vf, out);
}

// Round 8
// 149.730 us; speedup vs baseline: 1.0382x; 1.0382x over previous
//
#include <hip/hip_runtime.h>
#include <hip/hip_bf16.h>
#include <stdint.h>
#include <stddef.h>

#define NB 8
#define NT 2048
#define NC 1024
#define NH 128

typedef float f32x4 __attribute__((ext_vector_type(4)));
typedef short bf16x8 __attribute__((ext_vector_type(8)));
typedef short bf16x4 __attribute__((ext_vector_type(4)));

__device__ __forceinline__ unsigned short f2bf(float f) {
    union { float f; uint32_t u; } v; v.f = f;
    uint32_t u = v.u;
    u += 0x7fffu + ((u >> 16) & 1u);   // round-to-nearest-even
    return (unsigned short)(u >> 16);
}

// Direct global->LDS copy, 16 B/lane. lp must be wave-uniform.
__device__ __forceinline__ void gld16(const void* gp, void* lp) {
    __builtin_amdgcn_global_load_lds(
        (const __attribute__((address_space(1))) unsigned int*)gp,
        (__attribute__((address_space(3))) unsigned int*)lp, 16, 0, 0);
}

// K=16 bf16 MFMA (A/B = 4 bf16/lane, k = quad*4+j). Builtin name varies by
// ROCm vintage; instruction exists on gfx950 (cdna4_isa §10).
__device__ __forceinline__ f32x4 mfma16(bf16x4 a, bf16x4 b, f32x4 c) {
#if __has_builtin(__builtin_amdgcn_mfma_f32_16x16x16_bf16)
    return __builtin_amdgcn_mfma_f32_16x16x16_bf16(a, b, c, 0, 0, 0);
#elif __has_builtin(__builtin_amdgcn_mfma_f32_16x16x16bf16_1k)
    return __builtin_amdgcn_mfma_f32_16x16x16bf16_1k(a, b, c, 0, 0, 0);
#else
    f32x4 d;
    asm volatile("v_mfma_f32_16x16x16_bf16 %0, %1, %2, %3"
                 : "=v"(d) : "v"(a), "v"(b), "v"(c));
    return d;
#endif
}

// ===========================================================================
// Fragment-order layouts (lane = quad*16 + l16):
//   Qf/Kf [b][i=128][ks=4]  (1 KB/frag): lane holds X[t=i*16+l16][h=ks*32+quad*8+j]
//   Vf16  [b][nt*128+tk]    (512 B/frag): lane holds V[t=tk*16+quad*4+j][h=nt*16+l16]
//   Wtf   [g=24][kb=32]     (1 KB/frag): lane holds W_{g>>3}[k=kb*32+quad*8+j][n=(g&7)*16+l16]
// ===========================================================================

// ---------------------------------------------------------------------------
// Kernel 1: W fp32 [1024][128] -> Wtf fragment order. 192 blocks.
// ---------------------------------------------------------------------------
__global__ __launch_bounds__(256) void cast_w_kernel(const float* __restrict__ Wq,
                                                     const float* __restrict__ Wk,
                                                     const float* __restrict__ Wv,
                                                     unsigned short* __restrict__ Wtf) {
    int gid  = blockIdx.x * 256 + threadIdx.x;   // 0..49151
    int lane = gid & 63;
    int fs   = gid >> 6;                         // g*32 + kb
    int kb   = fs & 31;
    int g    = fs >> 5;                          // 0..23
    int w    = g >> 3;
    int g16  = g & 7;
    int quad = lane >> 4;
    int l16  = lane & 15;
    const float* src = (w == 0) ? Wq : ((w == 1) ? Wk : Wv);
    int n = g16 * 16 + l16;
    bf16x8 o;
#pragma unroll
    for (int j = 0; j < 8; ++j)
        o[j] = (short)f2bf(src[(size_t)(kb * 32 + quad * 8 + j) * 128 + n]);
    *(bf16x8*)(Wtf + (size_t)gid * 8) = o;
}

// ---------------------------------------------------------------------------
// Kernel 2: FUSED QKV projection — v4 "coalesced-x" (best measured ~43 µs).
// Only change vs R7: the V epilogue emits the K=16 fragment order (Vf16)
// for attn's in-register-P PV path.
// ---------------------------------------------------------------------------
#define CS2 392   // epilogue cs stride (shorts); 784 B = 49*16

__global__ __launch_bounds__(512, 2) void proj_kernel(const float* __restrict__ x,
                                                      const unsigned short* __restrict__ Wtf,
                                                      unsigned short* __restrict__ Qf,
                                                      unsigned short* __restrict__ Kf,
                                                      unsigned short* __restrict__ Vf) {
    __shared__ __align__(16) unsigned short wbuf[4][24 * 512];   // 96 KB; cs overlays
    __shared__ __align__(16) unsigned short abuf[2][64 * 128];   // 32 KB

    const int tid  = threadIdx.x;
    const int wave = tid >> 6;             // 0..7
    const int lane = tid & 63;
    const int quad = lane >> 4;
    const int l16  = lane & 15;
    const int bidx = blockIdx.x;           // 0..255
    const int rowbase = bidx * 64;
    const int b    = bidx >> 5;            // batch
    const int mh   = wave & 1;             // m-half (32 rows)
    const int nq   = wave >> 1;            // n-quarter (96 cols)

    const int arow = wave * 8 + (lane >> 3);
    const float* axp = x + (size_t)(rowbase + arow) * NC;
    const int aswz = (arow & 7) << 3;
    const int rswz = (l16 & 7) << 3;

    float4 aS[2][4];
    f32x4 acc0[6] = {};
    f32x4 acc1[6] = {};

#define STAGE(KB, BI) { _Pragma("unroll") \
    for (int i_ = 0; i_ < 3; ++i_) { \
        const int g_ = wave * 3 + i_; \
        gld16(Wtf + ((size_t)(g_ * 32 + (KB)) * 512) + lane * 8, &wbuf[BI][g_ * 512]); } }

#define LOADA(C, S) { _Pragma("unroll") \
    for (int i_ = 0; i_ < 4; ++i_) \
        aS[S][i_] = *(const float4*)(axp + (C) * 128 + i_ * 32 + (lane & 7) * 4); }

#define DSWRITE(C, S) { _Pragma("unroll") \
    for (int i_ = 0; i_ < 4; ++i_) { \
        bf16x4 t_; \
        t_[0] = (short)f2bf(aS[S][i_].x); t_[1] = (short)f2bf(aS[S][i_].y); \
        t_[2] = (short)f2bf(aS[S][i_].z); t_[3] = (short)f2bf(aS[S][i_].w); \
        *(bf16x4*)(&abuf[(C) & 1][arow * 128 + ((i_ * 32 + (lane & 7) * 4) ^ aswz)]) = t_; } }

#define BARW(N) { asm volatile("s_waitcnt vmcnt(" #N ") lgkmcnt(0)" ::: "memory"); \
                  __builtin_amdgcn_s_barrier(); }

#define TICK(K, CUR) { \
    const unsigned short* ab_ = abuf[((K) >> 2) & 1]; \
    const int t2_ = ((K) & 3) * 32 + quad * 8; \
    bf16x8 af0 = *(const bf16x8*)(ab_ + (mh * 32 + l16) * 128 + (t2_ ^ rswz)); \
    bf16x8 af1 = *(const bf16x8*)(ab_ + (mh * 32 + 16 + l16) * 128 + (t2_ ^ rswz)); \
    _Pragma("unroll") \
    for (int i_ = 0; i_ < 6; ++i_) { \
        bf16x8 wf_ = *(const bf16x8*)(&wbuf[CUR][(nq * 6 + i_) * 512 + lane * 8]); \
        acc0[i_] = __builtin_amdgcn_mfma_f32_16x16x32_bf16(af0, wf_, acc0[i_], 0, 0, 0); \
        acc1[i_] = __builtin_amdgcn_mfma_f32_16x16x32_bf16(af1, wf_, acc1[i_], 0, 0, 0); } }

    // ---- prologue ----
    LOADA(0, 0); LOADA(1, 1);
    STAGE(0, 0); STAGE(1, 1); STAGE(2, 2);
    asm volatile("s_waitcnt vmcnt(13)" ::: "memory");   // retire A(0)
    DSWRITE(0, 0);
    BARW(6);                                            // retire st(0)

    for (int c = 0; c < 6; ++c) {
        const int k0 = c * 4;
        LOADA(c + 2, c & 1);
        STAGE(k0 + 3, 3); TICK(k0 + 0, 0); BARW(10);
        STAGE(k0 + 4, 0); TICK(k0 + 1, 1); BARW(10);
        STAGE(k0 + 5, 1); TICK(k0 + 2, 2); BARW(6);
        STAGE(k0 + 6, 2); TICK(k0 + 3, 3); DSWRITE(c + 1, (c + 1) & 1); BARW(6);
    }
    STAGE(27, 3); TICK(24, 0); BARW(6);
    STAGE(28, 0); TICK(25, 1); BARW(6);
    STAGE(29, 1); TICK(26, 2); BARW(6);
    STAGE(30, 2); TICK(27, 3); DSWRITE(7, 1); BARW(6);
    STAGE(31, 3); TICK(28, 0); BARW(6);
    TICK(29, 1); BARW(3);
    TICK(30, 2); BARW(0);
    TICK(31, 3);
    asm volatile("s_waitcnt vmcnt(0) lgkmcnt(0)" ::: "memory");
    __builtin_amdgcn_s_barrier();

    // ---- epilogue: C (64 x 384) -> LDS bf16 (overlay wbuf), frag stores ----
    unsigned short* cs = (unsigned short*)wbuf;   // [64][CS2]
#pragma unroll
    for (int i = 0; i < 6; ++i) {
#pragma unroll
        for (int r = 0; r < 4; ++r) {
            cs[(mh * 32 +  0 + quad * 4 + r) * CS2 + nq * 96 + i * 16 + l16] = f2bf(acc0[i][r]);
            cs[(mh * 32 + 16 + quad * 4 + r) * CS2 + nq * 96 + i * 16 + l16] = f2bf(acc1[i][r]);
        }
    }
    __syncthreads();

    const int ibase = (rowbase & (NT - 1)) >> 4;   // 4 16-row tiles: ibase..+3
    unsigned short* qdst = Qf + (size_t)b * (NT * NH);
    unsigned short* kdst = Kf + (size_t)b * (NT * NH);
    unsigned short* vdst = Vf + (size_t)b * (NT * NH);

    // 48 slots, 6/wave: s<16 Q; s<32 K; s>=32 V (Vf16: 2 half-frags per slot).
#pragma unroll
    for (int j = 0; j < 6; ++j) {
        const int s = wave * 6 + j;
        if (s < 32) {
            const int isK = s >> 4;
            const int t   = s & 15;
            const int m   = t >> 2;
            const int ks  = t & 3;
            unsigned short* dst = isK ? kdst : qdst;
            bf16x8 v = *(const bf16x8*)(&cs[(m * 16 + l16) * CS2 + isK * 128 + ks * 32 + quad * 8]);
            *(bf16x8*)(dst + ((size_t)((ibase + m) * 4 + ks) * 64 + lane) * 8) = v;
        } else {
            const int vv = s - 32;          // nt*2 + pp
            const int nt = vv >> 1;
            const int pp = vv & 1;
#pragma unroll
            for (int ff = 0; ff < 2; ++ff) {
                const int t4 = pp * 2 + ff;
                bf16x4 v;
#pragma unroll
                for (int jj = 0; jj < 4; ++jj)
                    v[jj] = (short)cs[(t4 * 16 + quad * 4 + jj) * CS2 + 256 + nt * 16 + l16];
                *(bf16x4*)(vdst + (size_t)(nt * 128 + ibase + t4) * 256 + lane * 4) = v;
            }
        }
    }

#undef TICK
#undef BARW
#undef DSWRITE
#undef LOADA
#undef STAGE
}

// ---------------------------------------------------------------------------
// Kernel 3: flash attention, v5 "swapped-S, in-register P".
// Grid 256 (1 blk/CU), 512 thr (8 waves), block = 64 q-rows, 64-key tiles,
// 32 iters, 3-buffer counted vmcnt(4) — ONE barrier per iter.
// Wave (mh = w&1: 32 rows, kq = w>>1: 16-key slot):
//   S^T = mfma_16x16x32(K_frag, Q_frag)  (operands swapped!) -> lane holds
//   P[row=l16][keys quad*4+r] per m-tile. exp2 + f2bf pack in REGISTERS ->
//   bf16x4 = A-frag of mfma_16x16x16 (k=quad*4+j). PV: 16 K=16 MFMAs vs
//   Vf16 frags (ds_read_b64). No P LDS round-trip, no mid barrier.
//   O partial per kq -> 2-phase 4-way merge at end. Max-free softmax.
// ---------------------------------------------------------------------------
#define AKBUF(BI) (smem + (size_t)(BI) * 16384)
#define AVBUF(BI) (smem + (size_t)(BI) * 16384 + 8192)

__global__ __launch_bounds__(512, 1) void attn_kernel(const unsigned short* __restrict__ Qf,
                                                      const unsigned short* __restrict__ Kf,
                                                      const unsigned short* __restrict__ Vf,
                                                      float* __restrict__ out) {
    // shorts: [3 buffers][K 16x512 | V 32x256] = 96 KB; merge od overlays
    __shared__ __align__(16) unsigned short smem[3 * 16384];
    __shared__ float sl[8][32];                                  // 1 KB

    const int tid  = threadIdx.x;
    const int wave = tid >> 6;             // 0..7
    const int lane = tid & 63;
    const int quad = lane >> 4;
    const int l16  = lane & 15;
    const int bid  = blockIdx.x;           // 0..255
    const int b    = bid & 7;              // XCD pin
    const int iqg  = bid >> 3;             // 0..31 (64-row group)
    const int mh   = wave & 1;             // m-half (32 rows)
    const int kq   = wave >> 1;            // 16-key slot of each 64-key tile

    const unsigned short* qfp = Qf + (size_t)b * (NT * NH);
    const unsigned short* kfp = Kf + (size_t)b * (NT * NH);
    const unsigned short* vfp = Vf + (size_t)b * (NT * NH);   // Vf16 order

    // Q frags for this wave's two 16-row m-tiles
    const int iq0 = iqg * 4 + mh * 2;
    bf16x8 qf0[4], qf1[4];
#pragma unroll
    for (int ks = 0; ks < 4; ++ks) {
        qf0[ks] = *(const bf16x8*)(qfp + ((size_t)((iq0 + 0) * 4 + ks) * 64 + lane) * 8);
        qf1[ks] = *(const bf16x8*)(qfp + ((size_t)((iq0 + 1) * 4 + ks) * 64 + lane) * 8);
    }

    // stage 64-key tile j: waves 0-3 -> 16 K frags (1 KB); waves 4-7 ->
    // 16 V frag-pairs (2x512 B contiguous). 4 gld16/wave.
    auto stage = [&](int j, int bi) {
#pragma unroll
        for (int i = 0; i < 4; ++i) {
            if (wave < 4) {
                const int fid = wave * 4 + i;
                gld16(kfp + ((size_t)(j * 16 + fid) * 512) + lane * 8, AKBUF(bi) + fid * 512);
            } else {
                const int sid = (wave - 4) * 4 + i;   // nt*2 + pp
                const int nt = sid >> 1;
                const int pp = sid & 1;
                gld16(vfp + ((size_t)(nt * 128 + j * 4 + pp * 2) * 256) + lane * 8,
                      AVBUF(bi) + (nt * 4 + pp * 2) * 256);
            }
        }
    };

    // prologue: tiles 0,1 staged (Q loads older -> also retired by vmcnt(4))
    stage(0, 0);
    stage(1, 1);
    asm volatile("s_waitcnt vmcnt(4)" ::: "memory");
    __builtin_amdgcn_s_barrier();

    f32x4 O0[8] = {}, O1[8] = {};
    float ls0 = 0.f, ls1 = 0.f;
    const float scl2 = 0.03125f * 1.44269504088896340736f;  // (1/sqrt(C))*log2(e)

    int cur = 0;
    for (int j = 0; j < 32; ++j) {
        const int stb = (cur >= 1) ? cur - 1 : 2;     // (cur+2)%3
        if (j < 30) stage(j + 2, stb);
        const unsigned short* kb = AKBUF(cur);
        const unsigned short* vb = AVBUF(cur);

        // ---- S^T = K Q^T : wave's 16 keys x 2 m-tiles (swapped operands) ----
        f32x4 S0 = {}, S1 = {};
#pragma unroll
        for (int ks = 0; ks < 4; ++ks) {
            bf16x8 kf = *(const bf16x8*)(kb + (kq * 4 + ks) * 512 + lane * 8);
            S0 = __builtin_amdgcn_mfma_f32_16x16x32_bf16(kf, qf0[ks], S0, 0, 0, 0);
            S1 = __builtin_amdgcn_mfma_f32_16x16x32_bf16(kf, qf1[ks], S1, 0, 0, 0);
        }

        // ---- P = exp2(S*scl2) in-register; pack to K=16 A-frags ----
        bf16x4 pf0, pf1;
#pragma unroll
        for (int r = 0; r < 4; ++r) {
            float p0 = __builtin_amdgcn_exp2f(S0[r] * scl2);
            float p1 = __builtin_amdgcn_exp2f(S1[r] * scl2);
            ls0 += p0;
            ls1 += p1;
            pf0[r] = (short)f2bf(p0);
            pf1[r] = (short)f2bf(p1);
        }

        // ---- O += P V : 16 keys, all 8 nt, K=16 MFMA ----
#pragma unroll
        for (int nt = 0; nt < 8; ++nt) {
            bf16x4 vf = *(const bf16x4*)(vb + (nt * 4 + kq) * 256 + lane * 4);
            O0[nt] = mfma16(pf0, vf, O0[nt]);
            O1[nt] = mfma16(pf1, vf, O1[nt]);
        }

        // ---- retire stage(j+1) only; keep stage(j+2) in flight ----
        if (j < 30) {
            asm volatile("s_waitcnt vmcnt(4) lgkmcnt(0)" ::: "memory");
        } else {
            asm volatile("s_waitcnt vmcnt(0) lgkmcnt(0)" ::: "memory");
        }
        __builtin_amdgcn_s_barrier();
        cur = (cur >= 2) ? 0 : cur + 1;
    }

    // ---- row sums: reduce over quads (keys quad*4+r live across quads) ----
    ls0 += __shfl_xor(ls0, 16, 64);
    ls0 += __shfl_xor(ls0, 32, 64);
    ls1 += __shfl_xor(ls1, 16, 64);
    ls1 += __shfl_xor(ls1, 32, 64);
    if (quad == 0) {
        sl[wave][l16]      = ls0;   // rows of m-tile 0 (index = l16)
        sl[wave][16 + l16] = ls1;   // rows of m-tile 1
    }

    // ---- 2-phase 4-way kq merge through LDS overlay (67.6 KB <= 96 KB) ----
    float* od = (float*)smem;   // [4][32][132]
    if (kq >= 2) {
        float* myod = od + (size_t)((kq - 2) * 2 + mh) * 32 * 132;
#pragma unroll
        for (int nt = 0; nt < 8; ++nt) {
#pragma unroll
            for (int r = 0; r < 4; ++r) {
                myod[(quad * 4 + r) * 132 + nt * 16 + l16]      = O0[nt][r];
                myod[(16 + quad * 4 + r) * 132 + nt * 16 + l16] = O1[nt][r];
            }
        }
    }
    __syncthreads();
    if (kq < 2) {
        const float* pod = od + (size_t)(kq * 2 + mh) * 32 * 132;
#pragma unroll
        for (int nt = 0; nt < 8; ++nt) {
#pragma unroll
            for (int r = 0; r < 4; ++r) {
                O0[nt][r] += pod[(quad * 4 + r) * 132 + nt * 16 + l16];
                O1[nt][r] += pod[(16 + quad * 4 + r) * 132 + nt * 16 + l16];
            }
        }
    }
    __syncthreads();
    if (kq == 1) {
        float* myod = od + (size_t)mh * 32 * 132;
#pragma unroll
        for (int nt = 0; nt < 8; ++nt) {
#pragma unroll
            for (int r = 0; r < 4; ++r) {
                myod[(quad * 4 + r) * 132 + nt * 16 + l16]      = O0[nt][r];
                myod[(16 + quad * 4 + r) * 132 + nt * 16 + l16] = O1[nt][r];
            }
        }
    }
    __syncthreads();

    if (kq == 0) {
        float inv0[4], inv1[4];
#pragma unroll
        for (int r = 0; r < 4; ++r) {
            const int rr = quad * 4 + r;
            inv0[r] = 1.0f / (sl[mh][rr] + sl[2 + mh][rr] +
                              sl[4 + mh][rr] + sl[6 + mh][rr]);
            inv1[r] = 1.0f / (sl[mh][16 + rr] + sl[2 + mh][16 + rr] +
                              sl[4 + mh][16 + rr] + sl[6 + mh][16 + rr]);
        }
        const float* pod = od + (size_t)mh * 32 * 132;
        float* orow = out + ((size_t)b * NT + iqg * 64 + mh * 32) * NH;
#pragma unroll
        for (int nt = 0; nt < 8; ++nt) {
#pragma unroll
            for (int r = 0; r < 4; ++r) {
                float v0 = O0[nt][r] + pod[(quad * 4 + r) * 132 + nt * 16 + l16];
                float v1 = O1[nt][r] + pod[(16 + quad * 4 + r) * 132 + nt * 16 + l16];
                orow[(quad * 4 + r) * NH + nt * 16 + l16]      = v0 * inv0[r];
                orow[(16 + quad * 4 + r) * NH + nt * 16 + l16] = v1 * inv1[r];
            }
        }
    }
}

#undef AKBUF
#undef AVBUF

// ---------------------------------------------------------------------------
extern "C" void kernel_launch(void* const* d_in, const int* in_sizes, int n_in,
                              void* d_out, int out_size, void* d_ws, size_t ws_size,
                              hipStream_t stream) {
    const float* x  = (const float*)d_in[0];
    const float* Wk = (const float*)d_in[1];
    const float* Wq = (const float*)d_in[2];
    const float* Wv = (const float*)d_in[3];
    float* out = (float*)d_out;

    char* ws = (char*)d_ws;
    unsigned short* Qf  = (unsigned short*)(ws);                      //  4 MB
    unsigned short* Kf  = (unsigned short*)(ws + 4194304);            //  4 MB
    unsigned short* Vf  = (unsigned short*)(ws + 8388608);            //  4 MB (Vf16)
    unsigned short* Wtf = (unsigned short*)(ws + 12582912);           //  0.75 MB

    cast_w_kernel<<<192, 256, 0, stream>>>(Wq, Wk, Wv, Wtf);
    proj_kernel<<<256, 512, 0, stream>>>(x, Wtf, Qf, Kf, Vf);
    attn_kernel<<<256, 512, 0, stream>>>(Qf, Kf, Vf, out);
}